// Round 2
// baseline (5882.543 us; speedup 1.0000x reference)
//
#include <hip/hip_runtime.h>

// ---------------------------------------------------------------------------
// 2-layer GRU (H=256, B=512, T=1024, I=1) + FC on MI355X.
//
// Schedule (software pipeline over T-chunks of TC=64, chunk-lag 2):
//   prep                     : w_hh0/w_hh1 -> per-lane f16 MFMA B-fragments,
//                              w_ih1 -> f16 (once per call)
//   F(c), c=0..NC+1          : blocks [0,32)   rec layer0, chunk c      (c<NC)
//                              blocks [32,64)  rec layer1, chunk c-2    (c>=2)
//                              blocks [64,320) gemm gx1 = h0c @ w_ih1^T, chunk c-1
//   fc                       : out[b] = h1_last . w_fc + b_fc
//
// rec blocks: 512 thr (8 waves), 1 block/CU (VGPR-full, 256/wave via
// __launch_bounds__(512,2)); wave owns 32 h-columns x 3 gates; w_hh lives in
// 192 VGPRs of f16x8 B-fragments; h double-buffered in swizzled LDS.
// gemm blocks fill the remaining ~192 CUs and hide under the rec legs.
// Numerics: f16 MFMA inputs, f32 accum + f32 activations; h carried f16.
// ---------------------------------------------------------------------------

#define HH 256
#define TT 1024
#define BB 512
#define TC 64
#define NC (TT / TC)          // 16 chunks
#define NR (BB * TC)          // 32768 rows per chunk
#define F_GRID 320            // 32 rec0 + 32 rec1 + 256 gemm

typedef float    f32x4 __attribute__((ext_vector_type(4)));
typedef _Float16 f16x8 __attribute__((ext_vector_type(8)));

// element index into a swizzled [16][256] (or [128][256]) f16 LDS tile
__device__ __forceinline__ int swz(int row, int col) {
    return row * 256 + ((((col >> 3) ^ (row & 7))) << 3) + (col & 7);
}
__device__ __forceinline__ float fsigm(float v) {
    return __builtin_amdgcn_rcpf(1.f + __expf(-v));
}
__device__ __forceinline__ float ftanh(float v) {
    return 1.f - 2.f * __builtin_amdgcn_rcpf(__expf(2.f * v) + 1.f);
}

// ---------------------------------------------------------------------------
// Recurrent body. rid in [0,32): 16 batch rows. 8 waves; wave w owns cols
// {w*32+cl, w*32+16+cl} for all 3 gates. Per step: 8 swizzled ds_read_b128
// (h frags) + 48 mfma_16x16x32_f16 + activations + 8 b16 LDS writes + barrier.
// ---------------------------------------------------------------------------
template <int LAYER>
__device__ __forceinline__ void
rec_body(int rid, _Float16* sh, const _Float16* wfrag,
         const float* __restrict__ bhh, const float* __restrict__ bih,
         const float* __restrict__ x,        // L0: [512][1024]
         const _Float16* __restrict__ gx3,   // L1: 3 planes [NR][256]
         const float* __restrict__ wih0,     // L0: [768]
         _Float16* __restrict__ h0c,         // L0 out: [NR][256]
         float* __restrict__ hstate,         // [512][256] f32 carry
         int t0, bool first)
{
    const int tid = threadIdx.x;
    const int w = tid >> 6, l = tid & 63;
    const int cl = l & 15, kg = l >> 4;
    const int c0 = w * 32 + cl;          // first owned column
    const int r0 = kg * 4;               // C-frag row base (batch row in tile)
    const int b0 = rid * 16;

    // persistent B-fragments, pre-swizzled by prep: 48 coalesced dwordx4
    f16x8 wf[6][8];                      // [g*2+c2][kk]
#pragma unroll
    for (int i6 = 0; i6 < 6; ++i6)
#pragma unroll
        for (int kk = 0; kk < 8; ++kk)
            wf[i6][kk] = *(const f16x8*)(wfrag + (size_t)(((w * 6 + i6) * 8 + kk) * 64 + l) * 8);

    float bias[2][4];                    // {r: bhh+bih, z: bhh+bih, n: bhh, n: bih}
    float wi[2][3];
#pragma unroll
    for (int c2 = 0; c2 < 2; ++c2) {
        const int cc = c0 + c2 * 16;
        bias[c2][0] = bhh[cc] + bih[cc];
        bias[c2][1] = bhh[256 + cc] + bih[256 + cc];
        bias[c2][2] = bhh[512 + cc];
        bias[c2][3] = bih[512 + cc];
        if (LAYER == 0) {
            wi[c2][0] = wih0[cc]; wi[c2][1] = wih0[256 + cc]; wi[c2][2] = wih0[512 + cc];
        }
    }

    _Float16 hm[2][4];                   // h carry for owned (row,col) pairs
#pragma unroll
    for (int c2 = 0; c2 < 2; ++c2)
#pragma unroll
        for (int j = 0; j < 4; ++j) {
            float v = first ? 0.f : hstate[(size_t)(b0 + r0 + j) * 256 + c0 + c2 * 16];
            hm[c2][j] = (_Float16)v;
            sh[swz(r0 + j, c0 + c2 * 16)] = hm[c2][j];
        }
    __syncthreads();

    for (int t = 0; t < TC; ++t) {
        const int cur = t & 1;

        // per-step inputs, issued early (consumed after the MFMA phase)
        float xv[4];
        _Float16 gv[3][2][4];
        if (LAYER == 0) {
#pragma unroll
            for (int j = 0; j < 4; ++j)
                xv[j] = x[(size_t)(b0 + r0 + j) * TT + t0 + t];
        } else {
#pragma unroll
            for (int g = 0; g < 3; ++g)
#pragma unroll
                for (int c2 = 0; c2 < 2; ++c2)
#pragma unroll
                    for (int j = 0; j < 4; ++j)
                        gv[g][c2][j] = gx3[((size_t)g * NR + (size_t)(b0 + r0 + j) * TC + t) * 256 + c0 + c2 * 16];
        }

        // gh = h @ w_hh^T : 6 independent 8-deep MFMA chains
        f32x4 acc[6];
#pragma unroll
        for (int i6 = 0; i6 < 6; ++i6) {
            acc[i6][0] = 0.f; acc[i6][1] = 0.f; acc[i6][2] = 0.f; acc[i6][3] = 0.f;
        }
        const _Float16* hb = sh + cur * 4096;
#pragma unroll
        for (int kk = 0; kk < 8; ++kk) {
            const int kb = kk * 4 + kg;
            f16x8 a = *(const f16x8*)(hb + cl * 256 + ((kb ^ (cl & 7)) << 3));
#pragma unroll
            for (int i6 = 0; i6 < 6; ++i6)
                acc[i6] = __builtin_amdgcn_mfma_f32_16x16x32_f16(a, wf[i6][kk], acc[i6], 0, 0, 0);
        }

        // activations + state update (f32), write h_{t+1}
        _Float16* hbn = sh + (cur ^ 1) * 4096;
#pragma unroll
        for (int c2 = 0; c2 < 2; ++c2) {
            const int cc = c0 + c2 * 16;
#pragma unroll
            for (int j = 0; j < 4; ++j) {
                float gr, gz, gn;
                if (LAYER == 0) {
                    gr = xv[j] * wi[c2][0]; gz = xv[j] * wi[c2][1]; gn = xv[j] * wi[c2][2];
                } else {
                    gr = (float)gv[0][c2][j]; gz = (float)gv[1][c2][j]; gn = (float)gv[2][c2][j];
                }
                const float r  = fsigm(acc[c2][j] + bias[c2][0] + gr);
                const float z  = fsigm(acc[2 + c2][j] + bias[c2][1] + gz);
                const float nn = ftanh(gn + bias[c2][3] + r * (acc[4 + c2][j] + bias[c2][2]));
                const float h  = nn + z * ((float)hm[c2][j] - nn);
                hm[c2][j] = (_Float16)h;
                hbn[swz(r0 + j, cc)] = hm[c2][j];
                if (LAYER == 0)
                    h0c[((size_t)(b0 + r0 + j) * TC + t) * 256 + cc] = hm[c2][j];
            }
        }
        __syncthreads();
    }

#pragma unroll
    for (int c2 = 0; c2 < 2; ++c2)
#pragma unroll
        for (int j = 0; j < 4; ++j)
            hstate[(size_t)(b0 + r0 + j) * 256 + c0 + c2 * 16] = (float)hm[c2][j];
}

// ---------------------------------------------------------------------------
// gx1 chunk GEMM body: [128,256] x [256,768]^T -> 3 f16 gate planes.
// 8 waves (2M x 4N), A staged once in swizzled LDS, B dwordx2 from L2-hot
// f16 weights, one pass per gate plane.
// ---------------------------------------------------------------------------
__device__ __forceinline__ void
gemm_body(int gid, _Float16* Al, const _Float16* __restrict__ h0c,
          const _Float16* __restrict__ wi1h, _Float16* __restrict__ gx3)
{
    const int tid = threadIdx.x;
    const int m0 = gid * 128;
#pragma unroll
    for (int i = 0; i < 8; ++i) {
        const int u = i * 512 + tid;             // 4096 dwordx4 units
        const int row = u >> 5, kb = u & 31;
        f32x4 d = *(const f32x4*)(const void*)(h0c + (size_t)(m0 + row) * 256 + kb * 8);
        *(f32x4*)&Al[row * 256 + ((kb ^ (row & 7)) << 3)] = d;
    }
    __syncthreads();

    const int w = tid >> 6, l = tid & 63;
    const int wm = w >> 2, wn = w & 3, cl = l & 15, kg = l >> 4;

    for (int g = 0; g < 3; ++g) {
        f32x4 acc[4][4];
#pragma unroll
        for (int mi = 0; mi < 4; ++mi)
#pragma unroll
            for (int ni = 0; ni < 4; ++ni) {
                acc[mi][ni][0] = 0.f; acc[mi][ni][1] = 0.f;
                acc[mi][ni][2] = 0.f; acc[mi][ni][3] = 0.f;
            }
#pragma unroll
        for (int kk = 0; kk < 8; ++kk) {
            const int kb = kk * 4 + kg;
            f16x8 av[4], bv[4];
#pragma unroll
            for (int mi = 0; mi < 4; ++mi) {
                const int row = wm * 64 + mi * 16 + cl;
                av[mi] = *(const f16x8*)&Al[row * 256 + ((kb ^ (row & 7)) << 3)];
            }
#pragma unroll
            for (int ni = 0; ni < 4; ++ni) {
                const int n = g * 256 + wn * 64 + ni * 16 + cl;
                bv[ni] = *(const f16x8*)(const void*)(wi1h + (size_t)n * 256 + kb * 8);
            }
#pragma unroll
            for (int mi = 0; mi < 4; ++mi)
#pragma unroll
                for (int ni = 0; ni < 4; ++ni)
                    acc[mi][ni] = __builtin_amdgcn_mfma_f32_16x16x32_f16(av[mi], bv[ni], acc[mi][ni], 0, 0, 0);
        }
#pragma unroll
        for (int mi = 0; mi < 4; ++mi)
#pragma unroll
            for (int ni = 0; ni < 4; ++ni)
#pragma unroll
                for (int j = 0; j < 4; ++j) {
                    const size_t m = m0 + wm * 64 + mi * 16 + kg * 4 + j;
                    const int n = wn * 64 + ni * 16 + cl;
                    gx3[((size_t)g * NR + m) * 256 + n] = (_Float16)acc[mi][ni][j];
                }
    }
}

__global__ void __launch_bounds__(512, 2)
F_kernel(int c,
         const _Float16* __restrict__ wfrag0, const _Float16* __restrict__ wfrag1,
         const _Float16* __restrict__ wi1h,
         const float* __restrict__ x, const float* __restrict__ wih0,
         const float* __restrict__ bih0, const float* __restrict__ bhh0,
         const float* __restrict__ bih1, const float* __restrict__ bhh1,
         _Float16* __restrict__ h0c_w, const _Float16* __restrict__ h0c_r,
         _Float16* __restrict__ gx_w, const _Float16* __restrict__ gx_r,
         float* __restrict__ h0st, float* __restrict__ h1st)
{
    __shared__ __align__(16) _Float16 smem[32768];   // 64 KB (gemm A-tile / rec h dbuf)
    const int bid = blockIdx.x;
    if (bid < 32) {
        if (c < NC)
            rec_body<0>(bid, smem, wfrag0, bhh0, bih0, x, nullptr, wih0,
                        h0c_w, h0st, c * TC, c == 0);
    } else if (bid < 64) {
        if (c >= 2)
            rec_body<1>(bid - 32, smem, wfrag1, bhh1, bih1, nullptr, gx_r, nullptr,
                        nullptr, h1st, 0, c == 2);
    } else {
        if (c >= 1 && c <= NC)
            gemm_body(bid - 64, smem, h0c_r, wi1h, gx_w);
    }
}

// ---------------------------------------------------------------------------
// prep: w_hh0/w_hh1 -> per-lane fragment order f16; w_ih1 -> plain f16.
// ---------------------------------------------------------------------------
__global__ void __launch_bounds__(256)
prep_kernel(const float* __restrict__ whh0, const float* __restrict__ whh1,
            const float* __restrict__ wih1,
            _Float16* __restrict__ wfrag0, _Float16* __restrict__ wfrag1,
            _Float16* __restrict__ wi1h)
{
    const int u = blockIdx.x * 256 + threadIdx.x;    // 0..73727
    const int sec = u / 24576;
    const int v = u % 24576;
    const float* src;
    _Float16* dst;
    int off;
    if (sec < 2) {
        const int l = v & 63, q = v >> 6;
        const int kk = q & 7, p = q >> 3;
        const int c2 = p & 1, t3 = p >> 1;
        const int g = t3 % 3, w = t3 / 3;
        off = (g * 256 + w * 32 + c2 * 16 + (l & 15)) * 256 + kk * 32 + (l >> 4) * 8;
        src = (sec == 0) ? whh0 : whh1;
        dst = (sec == 0) ? wfrag0 : wfrag1;
    } else {
        off = v * 8;
        src = wih1;
        dst = wi1h;
    }
    f32x4 f0 = *(const f32x4*)(src + off);
    f32x4 f1 = *(const f32x4*)(src + off + 4);
    f16x8 h;
    h[0] = (_Float16)f0[0]; h[1] = (_Float16)f0[1];
    h[2] = (_Float16)f0[2]; h[3] = (_Float16)f0[3];
    h[4] = (_Float16)f1[0]; h[5] = (_Float16)f1[1];
    h[6] = (_Float16)f1[2]; h[7] = (_Float16)f1[3];
    *(f16x8*)(dst + (size_t)v * 8) = h;
}

// out[b] = h1[b,:] . w_fc + b_fc  (one wave per batch row)
__global__ void __launch_bounds__(64)
fc_kernel(const float* __restrict__ h, const float* __restrict__ wfc,
          const float* __restrict__ bfc, float* __restrict__ out)
{
    const int b = blockIdx.x, l = threadIdx.x;
    f32x4 hv = *(const f32x4*)(h + (size_t)b * 256 + l * 4);
    f32x4 wv = *(const f32x4*)(wfc + l * 4);
    float s = hv[0] * wv[0] + hv[1] * wv[1] + hv[2] * wv[2] + hv[3] * wv[3];
#pragma unroll
    for (int off = 32; off; off >>= 1) s += __shfl_down(s, off);
    if (l == 0) out[b] = s + bfc[0];
}

extern "C" void kernel_launch(void* const* d_in, const int* in_sizes, int n_in,
                              void* d_out, int out_size, void* d_ws, size_t ws_size,
                              hipStream_t stream)
{
    (void)in_sizes; (void)n_in; (void)out_size;

    const float* x    = (const float*)d_in[0];
    const float* wih0 = (const float*)d_in[1];
    const float* whh0 = (const float*)d_in[2];
    const float* bih0 = (const float*)d_in[3];
    const float* bhh0 = (const float*)d_in[4];
    const float* wih1 = (const float*)d_in[5];
    const float* whh1 = (const float*)d_in[6];
    const float* bih1 = (const float*)d_in[7];
    const float* bhh1 = (const float*)d_in[8];
    const float* wfc  = (const float*)d_in[9];
    const float* bfc  = (const float*)d_in[10];
    float* out = (float*)d_out;

    char* p = (char*)d_ws;
    _Float16* wfrag0 = (_Float16*)p; p += (size_t)196608 * 2;
    _Float16* wfrag1 = (_Float16*)p; p += (size_t)196608 * 2;
    _Float16* wi1h   = (_Float16*)p; p += (size_t)196608 * 2;
    _Float16* h0c[2];
    h0c[0] = (_Float16*)p; p += (size_t)NR * 256 * 2;
    h0c[1] = (_Float16*)p; p += (size_t)NR * 256 * 2;
    _Float16* gxc[2];
    gxc[0] = (_Float16*)p; p += (size_t)3 * NR * 256 * 2;
    gxc[1] = (_Float16*)p; p += (size_t)3 * NR * 256 * 2;
    float* h0st = (float*)p; p += (size_t)BB * 256 * 4;
    float* h1st = (float*)p; p += (size_t)BB * 256 * 4;
    if ((size_t)(p - (char*)d_ws) > ws_size) return;   // loud failure if ws too small

    prep_kernel<<<288, 256, 0, stream>>>(whh0, whh1, wih1, wfrag0, wfrag1, wi1h);

    for (int c = 0; c <= NC + 1; ++c) {
        F_kernel<<<F_GRID, 512, 0, stream>>>(
            c, wfrag0, wfrag1, wi1h, x, wih0,
            bih0, bhh0, bih1, bhh1,
            h0c[c & 1],            // rec0 writes chunk c
            h0c[(c ^ 1) & 1],      // gemm reads chunk c-1
            gxc[(c ^ 1) & 1],      // gemm writes chunk c-1
            gxc[c & 1],            // rec1 reads chunk c-2
            h0st, h1st);
    }
    fc_kernel<<<BB, 64, 0, stream>>>(h1st, wfc, bfc, out);
}

// Round 4
// 4969.867 us; speedup vs baseline: 1.1836x; 1.1836x over previous
//
#include <hip/hip_runtime.h>

// ---------------------------------------------------------------------------
// 2-layer GRU (H=256, B=512, T=1024, I=1) + FC on MI355X.
//
// Schedule (software pipeline over T-chunks of TC=64, chunk-lag 2):
//   prep                     : w_hh0/w_hh1 -> per-lane f16 MFMA B-fragments
//                              (interleaved col order), w_ih1 -> f16
//   F(c), c=0..NC+1          : blocks [0,32)   rec layer0, chunk c      (c<NC)
//                              blocks [32,64)  rec layer1, chunk c-2    (c>=2)
//                              blocks [64,320) gemm gx1 = h0c @ w_ih1^T, chunk c-1
//   fc                       : out[b] = h1_last . w_fc + b_fc
//
// ROUND-3 FIX (unmeasured in round 3 — GPU acquisition timeout; resubmitted):
// __launch_bounds__(512,1). Round-2's (512,2) produced a 128-VGPR cap -> the
// 192-VGPR persistent weight array spilled to scratch, re-loaded every step
// (350us/dispatch, MfmaUtil 4%). rec needs ~250 VGPRs; an 8-wave block admits
// 2 waves/EU -> 256-reg cap, which fits.
// Columns are interleaved (col = w*32 + 2*cl + c2) so per-step gx loads are
// 12 dwords (not 24 shorts) and h stores are packed f16x2/f32x2.
// ---------------------------------------------------------------------------

#define HH 256
#define TT 1024
#define BB 512
#define TC 64
#define NC (TT / TC)          // 16 chunks
#define NR (BB * TC)          // 32768 rows per chunk
#define F_GRID 320            // 32 rec0 + 32 rec1 + 256 gemm

typedef float    f32x4 __attribute__((ext_vector_type(4)));
typedef float    f32x2 __attribute__((ext_vector_type(2)));
typedef _Float16 f16x8 __attribute__((ext_vector_type(8)));
typedef _Float16 f16x2 __attribute__((ext_vector_type(2)));

// element index into a swizzled [rows][256] f16 LDS tile (8-col blocks XOR'd)
__device__ __forceinline__ int swz(int row, int col) {
    return row * 256 + ((((col >> 3) ^ (row & 7))) << 3) + (col & 7);
}
__device__ __forceinline__ float fsigm(float v) {
    return __builtin_amdgcn_rcpf(1.f + __expf(-v));
}
__device__ __forceinline__ float ftanh(float v) {
    return 1.f - 2.f * __builtin_amdgcn_rcpf(__expf(2.f * v) + 1.f);
}

// ---------------------------------------------------------------------------
// Recurrent body. rid in [0,32): 16 batch rows. 8 waves; wave w owns cols
// {w*32 + 2*cl + c2 : c2 in 0,1} for all 3 gates (c2 = MFMA n-tile).
// Per step: 8 swizzled ds_read_b128 (h frags) + 48 mfma_16x16x32_f16 +
// activations (48 trans/lane) + 4 ds_write_b32 + barrier.
// ---------------------------------------------------------------------------
template <int LAYER>
__device__ __forceinline__ void
rec_body(int rid, _Float16* sh, const _Float16* wfrag,
         const float* __restrict__ bhh, const float* __restrict__ bih,
         const float* __restrict__ x,        // L0: [512][1024]
         const _Float16* __restrict__ gx3,   // L1: 3 planes [NR][256]
         const float* __restrict__ wih0,     // L0: [768]
         _Float16* __restrict__ h0c,         // L0 out: [NR][256]
         float* __restrict__ hstate,         // [512][256] f32 carry
         int t0, bool first)
{
    const int tid = threadIdx.x;
    const int w = tid >> 6, l = tid & 63;
    const int cl = l & 15, kg = l >> 4;
    const int cb = w * 32 + 2 * cl;      // owned column pair base (c2 = +0/+1)
    const int r0 = kg * 4;               // C-frag row base (batch row in tile)
    const int b0 = rid * 16;

    // persistent B-fragments, pre-swizzled by prep: 48 coalesced dwordx4
    f16x8 wf[6][8];                      // [g*2+c2][kk]
#pragma unroll
    for (int i6 = 0; i6 < 6; ++i6)
#pragma unroll
        for (int kk = 0; kk < 8; ++kk)
            wf[i6][kk] = *(const f16x8*)(wfrag + (size_t)(((w * 6 + i6) * 8 + kk) * 64 + l) * 8);

    float bias[2][4];                    // {r: bhh+bih, z: bhh+bih, n: bhh, n: bih}
    float wi[2][3];
#pragma unroll
    for (int c2 = 0; c2 < 2; ++c2) {
        const int cc = cb + c2;
        bias[c2][0] = bhh[cc] + bih[cc];
        bias[c2][1] = bhh[256 + cc] + bih[256 + cc];
        bias[c2][2] = bhh[512 + cc];
        bias[c2][3] = bih[512 + cc];
        if (LAYER == 0) {
            wi[c2][0] = wih0[cc]; wi[c2][1] = wih0[256 + cc]; wi[c2][2] = wih0[512 + cc];
        }
    }

    // fp32 h carry for owned (row, colpair)
    float hm[2][4];
#pragma unroll
    for (int j = 0; j < 4; ++j) {
        f32x2 v = {0.f, 0.f};
        if (!first) v = *(const f32x2*)(hstate + (size_t)(b0 + r0 + j) * 256 + cb);
        hm[0][j] = v[0]; hm[1][j] = v[1];
        f16x2 hh; hh[0] = (_Float16)v[0]; hh[1] = (_Float16)v[1];
        *(f16x2*)(sh + (r0 + j) * 256 + ((((cb >> 3) ^ ((r0 + j) & 7))) << 3) + (cb & 7)) = hh;
    }

    // L0: stage this chunk's x into LDS (16 rows x 64 t, padded stride 65)
    float* xsf = (float*)(sh + 8192);
    if (LAYER == 0) {
        const int row = tid >> 5, tc2 = (tid & 31) * 2;
        const f32x2 d = *(const f32x2*)(x + (size_t)(b0 + row) * TT + t0 + tc2);
        xsf[row * 65 + tc2] = d[0];
        xsf[row * 65 + tc2 + 1] = d[1];
    }
    __syncthreads();

    for (int t = 0; t < TC; ++t) {
        const int cur = t & 1;

        // per-step inputs, issued early (consumed after the MFMA phase)
        float xv[4];
        f16x2 gv[3][4];
        if (LAYER == 0) {
#pragma unroll
            for (int j = 0; j < 4; ++j)
                xv[j] = xsf[(r0 + j) * 65 + t];
        } else {
#pragma unroll
            for (int g = 0; g < 3; ++g)
#pragma unroll
                for (int j = 0; j < 4; ++j)
                    gv[g][j] = *(const f16x2*)(gx3 + ((size_t)g * NR + (size_t)(b0 + r0 + j) * TC + t) * 256 + cb);
        }

        // gh = h @ w_hh^T : 6 independent 8-deep MFMA chains
        f32x4 acc[6];
#pragma unroll
        for (int i6 = 0; i6 < 6; ++i6) {
            acc[i6][0] = 0.f; acc[i6][1] = 0.f; acc[i6][2] = 0.f; acc[i6][3] = 0.f;
        }
        const _Float16* hb = sh + cur * 4096;
#pragma unroll
        for (int kk = 0; kk < 8; ++kk) {
            const int kb = kk * 4 + kg;
            f16x8 a = *(const f16x8*)(hb + cl * 256 + ((kb ^ (cl & 7)) << 3));
#pragma unroll
            for (int i6 = 0; i6 < 6; ++i6)
                acc[i6] = __builtin_amdgcn_mfma_f32_16x16x32_f16(a, wf[i6][kk], acc[i6], 0, 0, 0);
        }

        // activations + state update (f32), write h_{t+1} as packed f16x2
        _Float16* hbn = sh + (cur ^ 1) * 4096;
#pragma unroll
        for (int j = 0; j < 4; ++j) {
            f16x2 hh;
#pragma unroll
            for (int c2 = 0; c2 < 2; ++c2) {
                float gr, gz, gn;
                if (LAYER == 0) {
                    gr = xv[j] * wi[c2][0]; gz = xv[j] * wi[c2][1]; gn = xv[j] * wi[c2][2];
                } else {
                    gr = (float)gv[0][j][c2]; gz = (float)gv[1][j][c2]; gn = (float)gv[2][j][c2];
                }
                const float r  = fsigm(acc[c2][j] + bias[c2][0] + gr);
                const float z  = fsigm(acc[2 + c2][j] + bias[c2][1] + gz);
                const float nn = ftanh(gn + bias[c2][3] + r * (acc[4 + c2][j] + bias[c2][2]));
                const float h  = nn + z * (hm[c2][j] - nn);
                hm[c2][j] = h;
                hh[c2] = (_Float16)h;
            }
            *(f16x2*)(hbn + (r0 + j) * 256 + ((((cb >> 3) ^ ((r0 + j) & 7))) << 3) + (cb & 7)) = hh;
            if (LAYER == 0)
                *(f16x2*)(h0c + ((size_t)(b0 + r0 + j) * TC + t) * 256 + cb) = hh;
        }
        __syncthreads();
    }

#pragma unroll
    for (int j = 0; j < 4; ++j) {
        f32x2 v; v[0] = hm[0][j]; v[1] = hm[1][j];
        *(f32x2*)(hstate + (size_t)(b0 + r0 + j) * 256 + cb) = v;
    }
}

// ---------------------------------------------------------------------------
// gx1 chunk GEMM body: [128,256] x [256,768]^T -> 3 f16 gate planes.
// 8 waves (2M x 4N), A staged once in swizzled LDS, B from L2-hot f16
// weights, one pass per gate plane.
// ---------------------------------------------------------------------------
__device__ __forceinline__ void
gemm_body(int gid, _Float16* Al, const _Float16* __restrict__ h0c,
          const _Float16* __restrict__ wi1h, _Float16* __restrict__ gx3)
{
    const int tid = threadIdx.x;
    const int m0 = gid * 128;
#pragma unroll
    for (int i = 0; i < 8; ++i) {
        const int u = i * 512 + tid;             // 4096 dwordx4 units
        const int row = u >> 5, kb = u & 31;
        f32x4 d = *(const f32x4*)(const void*)(h0c + (size_t)(m0 + row) * 256 + kb * 8);
        *(f32x4*)&Al[row * 256 + ((kb ^ (row & 7)) << 3)] = d;
    }
    __syncthreads();

    const int w = tid >> 6, l = tid & 63;
    const int wm = w >> 2, wn = w & 3, cl = l & 15, kg = l >> 4;

    for (int g = 0; g < 3; ++g) {
        f32x4 acc[4][4];
#pragma unroll
        for (int mi = 0; mi < 4; ++mi)
#pragma unroll
            for (int ni = 0; ni < 4; ++ni) {
                acc[mi][ni][0] = 0.f; acc[mi][ni][1] = 0.f;
                acc[mi][ni][2] = 0.f; acc[mi][ni][3] = 0.f;
            }
#pragma unroll
        for (int kk = 0; kk < 8; ++kk) {
            const int kb = kk * 4 + kg;
            f16x8 av[4], bv[4];
#pragma unroll
            for (int mi = 0; mi < 4; ++mi) {
                const int row = wm * 64 + mi * 16 + cl;
                av[mi] = *(const f16x8*)&Al[row * 256 + ((kb ^ (row & 7)) << 3)];
            }
#pragma unroll
            for (int ni = 0; ni < 4; ++ni) {
                const int n = g * 256 + wn * 64 + ni * 16 + cl;
                bv[ni] = *(const f16x8*)(const void*)(wi1h + (size_t)n * 256 + kb * 8);
            }
#pragma unroll
            for (int mi = 0; mi < 4; ++mi)
#pragma unroll
                for (int ni = 0; ni < 4; ++ni)
                    acc[mi][ni] = __builtin_amdgcn_mfma_f32_16x16x32_f16(av[mi], bv[ni], acc[mi][ni], 0, 0, 0);
        }
#pragma unroll
        for (int mi = 0; mi < 4; ++mi)
#pragma unroll
            for (int ni = 0; ni < 4; ++ni)
#pragma unroll
                for (int j = 0; j < 4; ++j) {
                    const size_t m = m0 + wm * 64 + mi * 16 + kg * 4 + j;
                    const int n = wn * 64 + ni * 16 + cl;
                    gx3[((size_t)g * NR + m) * 256 + n] = (_Float16)acc[mi][ni][j];
                }
    }
}

__global__ void __launch_bounds__(512, 1)
F_kernel(int c,
         const _Float16* __restrict__ wfrag0, const _Float16* __restrict__ wfrag1,
         const _Float16* __restrict__ wi1h,
         const float* __restrict__ x, const float* __restrict__ wih0,
         const float* __restrict__ bih0, const float* __restrict__ bhh0,
         const float* __restrict__ bih1, const float* __restrict__ bhh1,
         _Float16* __restrict__ h0c_w, const _Float16* __restrict__ h0c_r,
         _Float16* __restrict__ gx_w, const _Float16* __restrict__ gx_r,
         float* __restrict__ h0st, float* __restrict__ h1st)
{
    __shared__ __align__(16) _Float16 smem[32768];   // 64 KB (gemm A-tile / rec h dbuf + xs)
    const int bid = blockIdx.x;
    if (bid < 32) {
        if (c < NC)
            rec_body<0>(bid, smem, wfrag0, bhh0, bih0, x, nullptr, wih0,
                        h0c_w, h0st, c * TC, c == 0);
    } else if (bid < 64) {
        if (c >= 2)
            rec_body<1>(bid - 32, smem, wfrag1, bhh1, bih1, nullptr, gx_r, nullptr,
                        nullptr, h1st, 0, c == 2);
    } else {
        if (c >= 1 && c <= NC)
            gemm_body(bid - 64, smem, h0c_r, wi1h, gx_w);
    }
}

// ---------------------------------------------------------------------------
// prep: w_hh0/w_hh1 -> per-lane fragment order f16 (interleaved col pairs);
// w_ih1 -> plain f16.
// ---------------------------------------------------------------------------
__global__ void __launch_bounds__(256)
prep_kernel(const float* __restrict__ whh0, const float* __restrict__ whh1,
            const float* __restrict__ wih1,
            _Float16* __restrict__ wfrag0, _Float16* __restrict__ wfrag1,
            _Float16* __restrict__ wi1h)
{
    const int u = blockIdx.x * 256 + threadIdx.x;    // 0..73727
    const int sec = u / 24576;
    const int v = u % 24576;
    const float* src;
    _Float16* dst;
    int off;
    if (sec < 2) {
        const int l = v & 63, q = v >> 6;
        const int kk = q & 7, p = q >> 3;
        const int i6 = p % 6, w = p / 6;
        const int g = i6 >> 1, c2 = i6 & 1;
        const int col = g * 256 + w * 32 + 2 * (l & 15) + c2;
        off = col * 256 + kk * 32 + (l >> 4) * 8;
        src = (sec == 0) ? whh0 : whh1;
        dst = (sec == 0) ? wfrag0 : wfrag1;
    } else {
        off = v * 8;
        src = wih1;
        dst = wi1h;
    }
    f32x4 f0 = *(const f32x4*)(src + off);
    f32x4 f1 = *(const f32x4*)(src + off + 4);
    f16x8 h;
    h[0] = (_Float16)f0[0]; h[1] = (_Float16)f0[1];
    h[2] = (_Float16)f0[2]; h[3] = (_Float16)f0[3];
    h[4] = (_Float16)f1[0]; h[5] = (_Float16)f1[1];
    h[6] = (_Float16)f1[2]; h[7] = (_Float16)f1[3];
    *(f16x8*)(dst + (size_t)v * 8) = h;
}

// out[b] = h1[b,:] . w_fc + b_fc  (one wave per batch row)
__global__ void __launch_bounds__(64)
fc_kernel(const float* __restrict__ h, const float* __restrict__ wfc,
          const float* __restrict__ bfc, float* __restrict__ out)
{
    const int b = blockIdx.x, l = threadIdx.x;
    f32x4 hv = *(const f32x4*)(h + (size_t)b * 256 + l * 4);
    f32x4 wv = *(const f32x4*)(wfc + l * 4);
    float s = hv[0] * wv[0] + hv[1] * wv[1] + hv[2] * wv[2] + hv[3] * wv[3];
#pragma unroll
    for (int off = 32; off; off >>= 1) s += __shfl_down(s, off);
    if (l == 0) out[b] = s + bfc[0];
}

extern "C" void kernel_launch(void* const* d_in, const int* in_sizes, int n_in,
                              void* d_out, int out_size, void* d_ws, size_t ws_size,
                              hipStream_t stream)
{
    (void)in_sizes; (void)n_in; (void)out_size;

    const float* x    = (const float*)d_in[0];
    const float* wih0 = (const float*)d_in[1];
    const float* whh0 = (const float*)d_in[2];
    const float* bih0 = (const float*)d_in[3];
    const float* bhh0 = (const float*)d_in[4];
    const float* wih1 = (const float*)d_in[5];
    const float* whh1 = (const float*)d_in[6];
    const float* bih1 = (const float*)d_in[7];
    const float* bhh1 = (const float*)d_in[8];
    const float* wfc  = (const float*)d_in[9];
    const float* bfc  = (const float*)d_in[10];
    float* out = (float*)d_out;

    char* p = (char*)d_ws;
    _Float16* wfrag0 = (_Float16*)p; p += (size_t)196608 * 2;
    _Float16* wfrag1 = (_Float16*)p; p += (size_t)196608 * 2;
    _Float16* wi1h   = (_Float16*)p; p += (size_t)196608 * 2;
    _Float16* h0c[2];
    h0c[0] = (_Float16*)p; p += (size_t)NR * 256 * 2;
    h0c[1] = (_Float16*)p; p += (size_t)NR * 256 * 2;
    _Float16* gxc[2];
    gxc[0] = (_Float16*)p; p += (size_t)3 * NR * 256 * 2;
    gxc[1] = (_Float16*)p; p += (size_t)3 * NR * 256 * 2;
    float* h0st = (float*)p; p += (size_t)BB * 256 * 4;
    float* h1st = (float*)p; p += (size_t)BB * 256 * 4;
    if ((size_t)(p - (char*)d_ws) > ws_size) return;   // loud failure if ws too small

    prep_kernel<<<288, 256, 0, stream>>>(whh0, whh1, wih1, wfrag0, wfrag1, wi1h);

    for (int c = 0; c <= NC + 1; ++c) {
        F_kernel<<<F_GRID, 512, 0, stream>>>(
            c, wfrag0, wfrag1, wi1h, x, wih0,
            bih0, bhh0, bih1, bhh1,
            h0c[c & 1],            // rec0 writes chunk c
            h0c[(c ^ 1) & 1],      // gemm reads chunk c-1
            gxc[(c ^ 1) & 1],      // gemm writes chunk c-1
            gxc[c & 1],            // rec1 reads chunk c-2
            h0st, h1st);
    }
    fc_kernel<<<BB, 64, 0, stream>>>(h1st, wfc, bfc, out);
}